// Round 5
// baseline (319.778 us; speedup 1.0000x reference)
//
#include <hip/hip_runtime.h>
#include <cstdint>
#include <cstddef>

#pragma clang fp contract(off)

#define A_N 76725
#define C_N 80
#define CA_N (A_N * 80)           // 6,138,000
#define MAXDET 200
#define NBIN 16
#define BCAP 256                  // per-bin capacity (expected ~120)
#define W_N 512                   // mask-NMS window
#define WORDS 8                   // W_N / 64
#define IMG_F 640.0f
#define THR0 0.975f
#define CNT_STRIDE 32             // ints; 128 B per counter -> own L2 line

typedef unsigned long long u64;

// ---------------------------------------------------------------------------
// IoU predicate — exact op sequence of the reference.
// ---------------------------------------------------------------------------
__device__ __forceinline__ bool iou_gt(float b0, float b1, float b2, float b3, float ab,
                                       float x0, float x1, float x2, float x3, float xa) {
    float ix1 = fmaxf(b0, x0);
    float iy1 = fmaxf(b1, x1);
    float ix2 = fminf(b2, x2);
    float iy2 = fminf(b3, x3);
    float iw = fmaxf(ix2 - ix1, 0.0f);
    float ih = fmaxf(iy2 - iy1, 0.0f);
    float inter = iw * ih;
    float den = ab + xa - inter;
    float iou = inter / den;
    return iou > 0.5f;
}

__device__ __forceinline__ float band_lo(int b) {
    return 0.975f - 0.025f * (float)b;
}

__device__ __forceinline__ u64 readlane64(u64 v, int src) {
    unsigned lo = __builtin_amdgcn_readlane((unsigned)v, src);
    unsigned hi = __builtin_amdgcn_readlane((unsigned)(v >> 32), src);
    return ((u64)hi << 32) | lo;
}

// ---------------------------------------------------------------------------
// K1: decode + bin-select + default-fill of outputs.
// ---------------------------------------------------------------------------
__global__ __launch_bounds__(256) void k_prep(const float* __restrict__ cls,
                                              const float* __restrict__ reg,
                                              const float* __restrict__ anc,
                                              float* __restrict__ boxes,
                                              int* __restrict__ gcnt,
                                              u64* __restrict__ gkeys,
                                              float4* __restrict__ out4,
                                              int nthreads) {
    int i = blockIdx.x * 256 + threadIdx.x;
    if (i < A_N) {
        float a0 = anc[i * 4 + 0], a1 = anc[i * 4 + 1];
        float a2 = anc[i * 4 + 2], a3 = anc[i * 4 + 3];
        float aw = a2 - a0;
        float ah = a3 - a1;
        float ax = a0 + 0.5f * aw;
        float ay = a1 + 0.5f * ah;
        float r0 = reg[i * 4 + 0], r1 = reg[i * 4 + 1];
        float r2 = reg[i * 4 + 2], r3 = reg[i * 4 + 3];
        float cx = ax + r0 * 0.1f * aw;
        float cy = ay + r1 * 0.1f * ah;
        float w = aw * expf(r2 * 0.2f);
        float h = ah * expf(r3 * 0.2f);
        float x1 = fminf(fmaxf(cx - 0.5f * w, 0.0f), IMG_F);
        float y1 = fminf(fmaxf(cy - 0.5f * h, 0.0f), IMG_F);
        float x2 = fminf(fmaxf(cx + 0.5f * w, 0.0f), IMG_F);
        float y2 = fminf(fmaxf(cy + 0.5f * h, 0.0f), IMG_F);
        boxes[i * 4 + 0] = x1;
        boxes[i * 4 + 1] = y1;
        boxes[i * 4 + 2] = x2;
        boxes[i * 4 + 3] = y2;
    }
    if (i < CA_N) {
        float s = cls[i];
        if (s > THR0) {
            int c = i % C_N;
            unsigned a = (unsigned)(i / C_N);
            int b = (int)((s - THR0) * 640.0f);
            b = b < 0 ? 0 : (b > (NBIN - 1) ? (NBIN - 1) : b);
            int slot = atomicAdd(&gcnt[(c * NBIN + b) * CNT_STRIDE], 1);
            if (slot < BCAP)
                gkeys[((size_t)(c * NBIN + b) << 8) + slot] =
                    ((u64)__float_as_uint(s) << 32) | (u64)(0xFFFFFFFFu - a);
        }
    }
    // default-fill role (grid-stride)
    const int n4 = (7 * CA_N) / 4;
    const int lab_lo = CA_N / 4;
    const int lab_hi = (2 * CA_N) / 4;
    for (int q = i; q < n4; q += nthreads) {
        float v = (q >= lab_lo && q < lab_hi) ? -1.0f : 0.0f;
        out4[q] = make_float4(v, v, v, v);
    }
}

// ---------------------------------------------------------------------------
// K2: sort each (class, bin) run in place (wave-local bitonic, desc).
// 80 blocks x 1024; wave w sorts bin (blockIdx.x, w).
// ---------------------------------------------------------------------------
__global__ __launch_bounds__(1024) void k_sort(const int* __restrict__ gcnt,
                                               u64* __restrict__ gkeys) {
    const int c = blockIdx.x;
    const int wave = threadIdx.x >> 6, lane = threadIdx.x & 63;
    __shared__ u64 buf[NBIN][BCAP];      // 32 KB

    int cnt = gcnt[(c * NBIN + wave) * CNT_STRIDE];
    cnt = cnt > BCAP ? BCAP : cnt;
    u64* gsrc = gkeys + ((size_t)(c * NBIN + wave) << 8);
    volatile u64* seg = buf[wave];
    for (int i = lane; i < cnt; i += 64) seg[i] = gsrc[i];
    int n2 = 64;
    while (n2 < cnt) n2 <<= 1;
    for (int i = cnt + lane; i < n2; i += 64) seg[i] = 0ull;
    __builtin_amdgcn_wave_barrier();
    for (int k = 2; k <= n2; k <<= 1) {
        for (int j = k >> 1; j > 0; j >>= 1) {
            for (int i0 = lane; i0 < n2; i0 += 64) {
                int ixj = i0 ^ j;
                if (ixj > i0) {
                    u64 u = seg[i0], v = seg[ixj];
                    bool up = ((i0 & k) == 0);
                    if (up ? (u < v) : (u > v)) { seg[i0] = v; seg[ixj] = u; }
                }
            }
            __builtin_amdgcn_wave_barrier();
        }
    }
    for (int i = lane; i < cnt; i += 64) gsrc[i] = seg[i];
}

// ---------------------------------------------------------------------------
// Chunk-of-64 greedy resolve over a sorted descending run (fallback path).
// Writes kept records directly to out and to kboxS/karea.
// ---------------------------------------------------------------------------
__device__ __forceinline__ int resolve_run(const u64* seg, int cnt, int kept,
                                           const float4* __restrict__ boxes4,
                                           float* __restrict__ out, int c,
                                           float4* kboxS, float* karea,
                                           float4* cbxS, float* car,
                                           unsigned int* mlo, unsigned int* mhi,
                                           unsigned char* supp, int* keptL,
                                           int tid, int lane) {
    for (int cs = 0; cs < cnt && kept < MAXDET; cs += 64) {
        int nc = (cnt - cs < 64) ? (cnt - cs) : 64;
        float4 rb = make_float4(0.f, 0.f, 0.f, 0.f);
        float rar = 0.f, rsc = 0.f;
        int rix = 0;
        if (tid < 64) {
            mlo[tid] = 0;
            mhi[tid] = 0;
            supp[tid] = (tid < nc) ? 0 : 1;
            if (tid < nc) {
                u64 key = seg[cs + tid];
                rix = (int)(0xFFFFFFFFu - (unsigned)(key & 0xFFFFFFFFull));
                rsc = __uint_as_float((unsigned)(key >> 32));
                rb = boxes4[rix];
                rar = (rb.z - rb.x) * (rb.w - rb.y);
                cbxS[tid] = rb;
                car[tid] = rar;
            }
        }
        __syncthreads();
        {
            int i = tid >> 4, jl = tid & 15;
            if (i < nc) {
                float4 x = cbxS[i];
                float xa = car[i];
                bool s = false;
                for (int j = jl; j < kept; j += 16) {
                    float4 kb = kboxS[j];
                    if (iou_gt(kb.x, kb.y, kb.z, kb.w, karea[j],
                               x.x, x.y, x.z, x.w, xa)) { s = true; break; }
                }
                if (s) supp[i] = 1;
            }
        }
        {
            int i = tid & 63, jb = tid >> 6;
            if (i < nc) {
                float4 b = cbxS[i];
                float ba = car[i];
                unsigned int l32 = 0, h32 = 0;
                for (int j = jb; j < nc; j += 16) {
                    if (j > i) {
                        float4 o = cbxS[j];
                        if (iou_gt(b.x, b.y, b.z, b.w, ba,
                                   o.x, o.y, o.z, o.w, car[j])) {
                            if (j < 32) l32 |= 1u << j;
                            else        h32 |= 1u << (j - 32);
                        }
                    }
                }
                if (l32) atomicOr(&mlo[i], l32);
                if (h32) atomicOr(&mhi[i], h32);
            }
        }
        __syncthreads();
        if (tid < 64) {
            bool alive = (lane < nc) && (supp[lane] == 0);
            unsigned int myLo = mlo[lane], myHi = mhi[lane];
            int kc = kept;
            while (kc < MAXDET) {
                u64 av = __ballot(alive);
                if (av == 0ull) break;
                int i = (int)__builtin_ctzll(av);
                unsigned int plo = (unsigned)__shfl((int)myLo, i, 64);
                unsigned int phi = (unsigned)__shfl((int)myHi, i, 64);
                u64 mi = ((u64)phi << 32) | plo;
                if (lane == i) {
                    kboxS[kc] = rb;
                    karea[kc] = rar;
                    size_t base = (size_t)c * A_N + (size_t)rix;
                    out[base] = rsc;
                    out[(size_t)CA_N + base] = (float)c;
                    size_t bo = (size_t)2 * CA_N + base * 4;
                    out[bo + 0] = rb.x;
                    out[bo + 1] = rb.y;
                    out[bo + 2] = rb.z;
                    out[bo + 3] = rb.w;
                    out[(size_t)6 * CA_N + base] = 1.0f;
                    alive = false;
                }
                if ((mi >> lane) & 1ull) alive = false;
                kc++;
            }
            if (lane == 0) *keptL = kc;
        }
        __syncthreads();
        kept = *keptL;
    }
    return kept;
}

// ---------------------------------------------------------------------------
// K3: mask-based greedy NMS per class. One block (1024 thr) per class.
// Window of first W_N sorted candidates: parallel IoU bitmask build, then a
// single serial scan (wave 0, ~170 cyc per kept). Fallback to chunked resolve
// for candidates beyond the window / score bands below 0.975 (never in
// practice — counters confirm).
// ---------------------------------------------------------------------------
__global__ __launch_bounds__(1024) void k_resolve(const float* __restrict__ cls,
                                                  const float* __restrict__ boxes,
                                                  const int* __restrict__ gcnt,
                                                  const u64* __restrict__ gkeys,
                                                  float* __restrict__ out) {
    const int c = blockIdx.x;
    const int tid = threadIdx.x;
    const int lane = tid & 63;
    const float4* boxes4 = (const float4*)boxes;

    __shared__ u64 maskL[W_N * WORDS];   // 32 KB (also reused as 4096-u64 key buf)
    __shared__ float4 cbx[W_N];          // 8 KB
    __shared__ float car[W_N];           // 2 KB
    __shared__ int cntb[NBIN], off[NBIN];
    __shared__ float4 kboxS[MAXDET];
    __shared__ float karea[MAXDET];
    __shared__ float4 cbxS[64];
    __shared__ float car64[64];
    __shared__ unsigned int mlo[64], mhi[64];
    __shared__ unsigned char supp[64];
    __shared__ u64 keptwS[WORDS];
    __shared__ int keptCtr, keptSh, cntL, keptL;

    // --- bin counts + offsets (global order: bin 15 first, each desc) -------
    if (tid < NBIN) {
        int v = gcnt[(c * NBIN + tid) * CNT_STRIDE];
        cntb[tid] = v > BCAP ? BCAP : v;
    }
    if (tid == 0) keptCtr = 0;
    __syncthreads();
    if (tid < NBIN) {
        int s = 0;
        for (int bb = NBIN - 1; bb > tid; --bb) s += cntb[bb];
        off[tid] = s;
    }
    __syncthreads();
    const int N = off[0] + cntb[0];
    const int NW = N < W_N ? N : W_N;

    // --- load window candidates --------------------------------------------
    int myA = 0;
    float mySc = 0.f, myArea = 0.f;
    float4 myBox = make_float4(0.f, 0.f, 0.f, 0.f);
    if (tid < NW) {
        int b = NBIN - 1;
        for (; b >= 0; --b)
            if (tid >= off[b] && tid < off[b] + cntb[b]) break;
        u64 key = gkeys[((size_t)(c * NBIN + b) << 8) + (tid - off[b])];
        myA = (int)(0xFFFFFFFFu - (unsigned)(key & 0xFFFFFFFFull));
        mySc = __uint_as_float((unsigned)(key >> 32));
        myBox = boxes4[myA];
        myArea = (myBox.z - myBox.x) * (myBox.w - myBox.y);
        cbx[tid] = myBox;
        car[tid] = myArea;
    }
    __syncthreads();

    // --- parallel mask build: thread t -> word w = t&7, rows ig*4..ig*4+3 ---
    {
        int w = tid & 7, ig = tid >> 3;          // ig in [0,128)
        int r0 = ig * 4;
        int jbase = w * 64;
        if (r0 < NW) {
            if (jbase + 63 <= r0) {              // all j <= min row: zero words
                for (int r = 0; r < 4; ++r)
                    if (r0 + r < NW) maskL[(size_t)(r0 + r) * WORDS + w] = 0ull;
            } else {
                float4 b0 = cbx[r0];
                float4 b1 = (r0 + 1 < NW) ? cbx[r0 + 1] : b0;
                float4 b2 = (r0 + 2 < NW) ? cbx[r0 + 2] : b0;
                float4 b3 = (r0 + 3 < NW) ? cbx[r0 + 3] : b0;
                float a0 = car[r0];
                float a1 = (r0 + 1 < NW) ? car[r0 + 1] : a0;
                float a2 = (r0 + 2 < NW) ? car[r0 + 2] : a0;
                float a3 = (r0 + 3 < NW) ? car[r0 + 3] : a0;
                u64 m0 = 0, m1 = 0, m2 = 0, m3 = 0;
                int jend = jbase + 64 < NW ? jbase + 64 : NW;
                for (int j = jbase; j < jend; ++j) {
                    float4 o = cbx[j];
                    float oa = car[j];
                    u64 bit = 1ull << (j - jbase);
                    if (j > r0 && iou_gt(b0.x, b0.y, b0.z, b0.w, a0,
                                         o.x, o.y, o.z, o.w, oa)) m0 |= bit;
                    if (j > r0 + 1 && iou_gt(b1.x, b1.y, b1.z, b1.w, a1,
                                             o.x, o.y, o.z, o.w, oa)) m1 |= bit;
                    if (j > r0 + 2 && iou_gt(b2.x, b2.y, b2.z, b2.w, a2,
                                             o.x, o.y, o.z, o.w, oa)) m2 |= bit;
                    if (j > r0 + 3 && iou_gt(b3.x, b3.y, b3.z, b3.w, a3,
                                             o.x, o.y, o.z, o.w, oa)) m3 |= bit;
                }
                maskL[(size_t)r0 * WORDS + w] = m0;
                if (r0 + 1 < NW) maskL[(size_t)(r0 + 1) * WORDS + w] = m1;
                if (r0 + 2 < NW) maskL[(size_t)(r0 + 2) * WORDS + w] = m2;
                if (r0 + 3 < NW) maskL[(size_t)(r0 + 3) * WORDS + w] = m3;
            }
        }
    }
    __syncthreads();

    // --- serial scan (wave 0): per kept = 1 parallel ds_read_b64 + ORs -----
    if (tid < 64) {
        u64 rem = 0, keptw = 0;
        int kept = 0;
        for (int w0 = 0; w0 < WORDS && kept < MAXDET; ++w0) {
            int nb = NW - w0 * 64;
            if (nb <= 0) break;
            u64 valw = nb >= 64 ? ~0ull : ((1ull << nb) - 1ull);
            u64 alive = ~readlane64(rem, w0) & valw;
            while (alive && kept < MAXDET) {
                int ii = (int)__builtin_ctzll(alive);
                int i = w0 * 64 + ii;
                u64 m = 0;
                if (lane < WORDS) m = maskL[(size_t)i * WORDS + lane];
                rem |= m;
                if (lane == w0) keptw |= 1ull << ii;
                kept++;
                u64 mw0 = readlane64(m, w0);
                alive &= ~(mw0 | (1ull << ii));
            }
        }
        if (lane < WORDS) keptwS[lane] = keptw;
        if (lane == 0) keptSh = kept;
    }
    __syncthreads();

    // --- window-kept: write records to out + kboxS for fallback ------------
    if (tid < NW) {
        if ((keptwS[tid >> 6] >> (tid & 63)) & 1ull) {
            int slot = atomicAdd(&keptCtr, 1);
            kboxS[slot] = myBox;
            karea[slot] = myArea;
            size_t base = (size_t)c * A_N + (size_t)myA;
            out[base] = mySc;
            out[(size_t)CA_N + base] = (float)c;
            size_t bo = (size_t)2 * CA_N + base * 4;
            out[bo + 0] = myBox.x;
            out[bo + 1] = myBox.y;
            out[bo + 2] = myBox.z;
            out[bo + 3] = myBox.w;
            out[(size_t)6 * CA_N + base] = 1.0f;
        }
    }
    __syncthreads();
    int kept = keptSh;

    // --- fallback 1: band-0 candidates beyond the window (rare) ------------
    if (kept < MAXDET && N > NW) {
        u64* keysF = maskL;                  // reuse 4096-u64 region
        for (int t2 = NW + tid; t2 < N; t2 += 1024) {
            int b = NBIN - 1;
            for (; b >= 0; --b)
                if (t2 >= off[b] && t2 < off[b] + cntb[b]) break;
            keysF[t2 - NW] = gkeys[((size_t)(c * NBIN + b) << 8) + (t2 - off[b])];
        }
        __syncthreads();
        kept = resolve_run(keysF, N - NW, kept, boxes4, out, c,
                           kboxS, karea, cbxS, car64, mlo, mhi, supp, &keptL,
                           tid, lane);
    }

    // --- fallback 2: score bands below 0.975 (never in practice) -----------
    if (kept < MAXDET) {
        u64* keysF = maskL;
        for (int band = 1;; ++band) {
            float hiB = band_lo(band - 1);
            float lo = band_lo(band);
            bool last = (lo <= 0.1f);
            float loEff = last ? 0.1f : lo;
            if (tid == 0) cntL = 0;
            __syncthreads();
            for (int a = tid; a < A_N; a += 1024) {
                float s = cls[(size_t)a * C_N + c];
                if (s > loEff && s <= hiB) {
                    int p = atomicAdd(&cntL, 1);
                    if (p < 4096)
                        keysF[p] = ((u64)__float_as_uint(s) << 32) |
                                   (u64)(0xFFFFFFFFu - (unsigned)a);
                }
            }
            __syncthreads();
            int cnt = cntL < 4096 ? cntL : 4096;
            int n2 = 64;
            while (n2 < cnt) n2 <<= 1;
            for (int i = cnt + tid; i < n2; i += 1024) keysF[i] = 0ull;
            __syncthreads();
            for (int k = 2; k <= n2; k <<= 1) {
                for (int j = k >> 1; j > 0; j >>= 1) {
                    for (int i = tid; i < n2; i += 1024) {
                        int ixj = i ^ j;
                        if (ixj > i) {
                            u64 u = keysF[i], v = keysF[ixj];
                            bool up = ((i & k) == 0);
                            if (up ? (u < v) : (u > v)) { keysF[i] = v; keysF[ixj] = u; }
                        }
                    }
                    __syncthreads();
                }
            }
            kept = resolve_run(keysF, cnt, kept, boxes4, out, c,
                               kboxS, karea, cbxS, car64, mlo, mhi, supp, &keptL,
                               tid, lane);
            if (kept >= MAXDET || last) break;
        }
    }
}

extern "C" void kernel_launch(void* const* d_in, const int* in_sizes, int n_in,
                              void* d_out, int out_size, void* d_ws, size_t ws_size,
                              hipStream_t stream) {
    const float* cls = (const float*)d_in[0];   // [1, A, C]
    const float* reg = (const float*)d_in[1];   // [1, A, 4]
    const float* anc = (const float*)d_in[2];   // [A, 4]
    float* out = (float*)d_out;

    // workspace layout (~4 MB)
    int* gcnt = (int*)d_ws;                                  // C*NBIN*CNT_STRIDE ints
    float* boxes = (float*)(gcnt + C_N * NBIN * CNT_STRIDE); // 4*A floats
    u64* gkeys = (u64*)(boxes + 4 * A_N);                    // C*NBIN*BCAP u64

    hipMemsetAsync(gcnt, 0, C_N * NBIN * CNT_STRIDE * sizeof(int), stream);

    const int nblocks = (CA_N + 255) / 256;
    k_prep<<<nblocks, 256, 0, stream>>>(cls, reg, anc, boxes, gcnt, gkeys,
                                        (float4*)d_out, nblocks * 256);

    k_sort<<<C_N, 1024, 0, stream>>>(gcnt, gkeys);

    k_resolve<<<C_N, 1024, 0, stream>>>(cls, boxes, gcnt, gkeys, out);
}

// Round 6
// 305.119 us; speedup vs baseline: 1.0480x; 1.0480x over previous
//
#include <hip/hip_runtime.h>
#include <cstdint>
#include <cstddef>

#pragma clang fp contract(off)

#define A_N 76725
#define C_N 80
#define CA_N (A_N * 80)           // 6,138,000
#define MAXDET 200
#define NBIN 16
#define BCAP 256                  // per-bin capacity (expected ~120)
#define W_N 512                   // mask-NMS window
#define WORDS 8                   // W_N / 64
#define IMG_F 640.0f
#define THR0 0.975f
#define CNT_STRIDE 32             // ints; 128 B per counter -> own L2 line

typedef unsigned long long u64;

// ---------------------------------------------------------------------------
// IoU predicate — exact op sequence of the reference.
// ---------------------------------------------------------------------------
__device__ __forceinline__ bool iou_gt(float b0, float b1, float b2, float b3, float ab,
                                       float x0, float x1, float x2, float x3, float xa) {
    float ix1 = fmaxf(b0, x0);
    float iy1 = fmaxf(b1, x1);
    float ix2 = fminf(b2, x2);
    float iy2 = fminf(b3, x3);
    float iw = fmaxf(ix2 - ix1, 0.0f);
    float ih = fmaxf(iy2 - iy1, 0.0f);
    float inter = iw * ih;
    float den = ab + xa - inter;
    float iou = inter / den;
    return iou > 0.5f;
}

__device__ __forceinline__ float band_lo(int b) {
    return 0.975f - 0.025f * (float)b;
}

__device__ __forceinline__ u64 readlane64(u64 v, int src) {
    unsigned lo = __builtin_amdgcn_readlane((unsigned)v, src);
    unsigned hi = __builtin_amdgcn_readlane((unsigned)(v >> 32), src);
    return ((u64)hi << 32) | lo;
}

// ---------------------------------------------------------------------------
// K1: decode + bin-select + default-fill of outputs.
// ---------------------------------------------------------------------------
__global__ __launch_bounds__(256) void k_prep(const float* __restrict__ cls,
                                              const float* __restrict__ reg,
                                              const float* __restrict__ anc,
                                              float* __restrict__ boxes,
                                              int* __restrict__ gcnt,
                                              u64* __restrict__ gkeys,
                                              float4* __restrict__ out4,
                                              int nthreads) {
    int i = blockIdx.x * 256 + threadIdx.x;
    if (i < A_N) {
        float a0 = anc[i * 4 + 0], a1 = anc[i * 4 + 1];
        float a2 = anc[i * 4 + 2], a3 = anc[i * 4 + 3];
        float aw = a2 - a0;
        float ah = a3 - a1;
        float ax = a0 + 0.5f * aw;
        float ay = a1 + 0.5f * ah;
        float r0 = reg[i * 4 + 0], r1 = reg[i * 4 + 1];
        float r2 = reg[i * 4 + 2], r3 = reg[i * 4 + 3];
        float cx = ax + r0 * 0.1f * aw;
        float cy = ay + r1 * 0.1f * ah;
        float w = aw * expf(r2 * 0.2f);
        float h = ah * expf(r3 * 0.2f);
        float x1 = fminf(fmaxf(cx - 0.5f * w, 0.0f), IMG_F);
        float y1 = fminf(fmaxf(cy - 0.5f * h, 0.0f), IMG_F);
        float x2 = fminf(fmaxf(cx + 0.5f * w, 0.0f), IMG_F);
        float y2 = fminf(fmaxf(cy + 0.5f * h, 0.0f), IMG_F);
        boxes[i * 4 + 0] = x1;
        boxes[i * 4 + 1] = y1;
        boxes[i * 4 + 2] = x2;
        boxes[i * 4 + 3] = y2;
    }
    if (i < CA_N) {
        float s = cls[i];
        if (s > THR0) {
            int c = i % C_N;
            unsigned a = (unsigned)(i / C_N);
            int b = (int)((s - THR0) * 640.0f);
            b = b < 0 ? 0 : (b > (NBIN - 1) ? (NBIN - 1) : b);
            int slot = atomicAdd(&gcnt[(c * NBIN + b) * CNT_STRIDE], 1);
            if (slot < BCAP)
                gkeys[((size_t)(c * NBIN + b) << 8) + slot] =
                    ((u64)__float_as_uint(s) << 32) | (u64)(0xFFFFFFFFu - a);
        }
    }
    const int n4 = (7 * CA_N) / 4;
    const int lab_lo = CA_N / 4;
    const int lab_hi = (2 * CA_N) / 4;
    for (int q = i; q < n4; q += nthreads) {
        float v = (q >= lab_lo && q < lab_hi) ? -1.0f : 0.0f;
        out4[q] = make_float4(v, v, v, v);
    }
}

// ---------------------------------------------------------------------------
// K2: per-bin wave sort + window gather.  80 blocks x 1024.
// Wave w sorts bin (c, w) desc in LDS, writes sorted keys back to gkeys
// (fallback-1 needs them), then the block gathers the first W_N sorted
// candidates into contiguous winBox/winArea/winScr/winIdx arrays.
// ---------------------------------------------------------------------------
__global__ __launch_bounds__(1024) void k_sortgather(const int* __restrict__ gcnt,
                                                     u64* __restrict__ gkeys,
                                                     const float4* __restrict__ boxes4,
                                                     float4* __restrict__ winBox,
                                                     float* __restrict__ winArea,
                                                     float* __restrict__ winScr,
                                                     int* __restrict__ winIdx) {
    const int c = blockIdx.x;
    const int tid = threadIdx.x;
    const int wave = tid >> 6, lane = tid & 63;
    __shared__ u64 buf[NBIN][BCAP];      // 32 KB
    __shared__ int cntb[NBIN], off[NBIN];

    int cnt = gcnt[(c * NBIN + wave) * CNT_STRIDE];
    cnt = cnt > BCAP ? BCAP : cnt;
    if (lane == 0) cntb[wave] = cnt;
    u64* gsrc = gkeys + ((size_t)(c * NBIN + wave) << 8);
    volatile u64* seg = buf[wave];
    for (int i = lane; i < cnt; i += 64) seg[i] = gsrc[i];
    int n2 = 64;
    while (n2 < cnt) n2 <<= 1;
    for (int i = cnt + lane; i < n2; i += 64) seg[i] = 0ull;
    __builtin_amdgcn_wave_barrier();
    for (int k = 2; k <= n2; k <<= 1) {
        for (int j = k >> 1; j > 0; j >>= 1) {
            for (int i0 = lane; i0 < n2; i0 += 64) {
                int ixj = i0 ^ j;
                if (ixj > i0) {
                    u64 u = seg[i0], v = seg[ixj];
                    bool up = ((i0 & k) == 0);
                    if (up ? (u < v) : (u > v)) { seg[i0] = v; seg[ixj] = u; }
                }
            }
            __builtin_amdgcn_wave_barrier();
        }
    }
    for (int i = lane; i < cnt; i += 64) gsrc[i] = seg[i];
    __syncthreads();

    if (tid < NBIN) {
        int s = 0;
        for (int bb = NBIN - 1; bb > tid; --bb) s += cntb[bb];
        off[tid] = s;
    }
    __syncthreads();
    const int N = off[0] + cntb[0];
    const int NW = N < W_N ? N : W_N;

    for (int i = tid; i < NW; i += 1024) {
        int b = NBIN - 1;
        for (; b >= 0; --b)
            if (i >= off[b] && i < off[b] + cntb[b]) break;
        u64 key = buf[b][i - off[b]];
        int a = (int)(0xFFFFFFFFu - (unsigned)(key & 0xFFFFFFFFull));
        float4 bx = boxes4[a];
        winBox[c * W_N + i] = bx;
        winArea[c * W_N + i] = (bx.z - bx.x) * (bx.w - bx.y);
        winScr[c * W_N + i] = __uint_as_float((unsigned)(key >> 32));
        winIdx[c * W_N + i] = a;
    }
}

// ---------------------------------------------------------------------------
// K3: multi-block mask build.  Grid (8, 80): block (w, c) computes mask word
// w (cols 64w..64w+63) for all rows, upper-triangular (row suppresses col>row).
// Rows >= rmax get explicit zeros so the scan reads clean data.
// ---------------------------------------------------------------------------
__global__ __launch_bounds__(256) void k_mask(const int* __restrict__ gcnt,
                                              const float4* __restrict__ winBox,
                                              const float* __restrict__ winArea,
                                              u64* __restrict__ maskG) {
    const int w = blockIdx.x, c = blockIdx.y;
    const int tid = threadIdx.x;
    __shared__ float4 jb[64];
    __shared__ float ja[64];
    __shared__ int cs[NBIN];

    if (tid < NBIN) {
        int v = gcnt[(c * NBIN + tid) * CNT_STRIDE];
        cs[tid] = v > BCAP ? BCAP : v;
    }
    __syncthreads();
    int N = 0;
    for (int b = 0; b < NBIN; ++b) N += cs[b];
    const int NW = N < W_N ? N : W_N;
    const int jg0 = w * 64;

    if (tid < 64 && jg0 + tid < NW) {
        jb[tid] = winBox[c * W_N + jg0 + tid];
        ja[tid] = winArea[c * W_N + jg0 + tid];
    }
    __syncthreads();

    int rmax = 64 * (w + 1);
    rmax = rmax < NW ? rmax : NW;
    const int jend = (NW - jg0) < 64 ? (NW - jg0) : 64;

    for (int r = tid; r < W_N; r += 256) {
        u64 m = 0;
        if (r < rmax) {
            float4 rb = winBox[c * W_N + r];
            float ra = winArea[c * W_N + r];
            for (int jj = 0; jj < jend; ++jj) {
                int jg = jg0 + jj;
                if (jg > r) {
                    float4 o = jb[jj];
                    if (iou_gt(rb.x, rb.y, rb.z, rb.w, ra,
                               o.x, o.y, o.z, o.w, ja[jj]))
                        m |= 1ull << jj;
                }
            }
        }
        maskG[((size_t)(c * WORDS + w)) * W_N + r] = m;
    }
}

// ---------------------------------------------------------------------------
// Chunk-of-64 greedy resolve over a sorted descending run (fallback path).
// ---------------------------------------------------------------------------
__device__ __forceinline__ int resolve_run(const u64* seg, int cnt, int kept,
                                           const float4* __restrict__ boxes4,
                                           float* __restrict__ out, int c,
                                           float4* kboxS, float* karea,
                                           float4* cbxS, float* car,
                                           unsigned int* mlo, unsigned int* mhi,
                                           unsigned char* supp, int* keptL,
                                           int tid, int lane) {
    for (int cs = 0; cs < cnt && kept < MAXDET; cs += 64) {
        int nc = (cnt - cs < 64) ? (cnt - cs) : 64;
        float4 rb = make_float4(0.f, 0.f, 0.f, 0.f);
        float rar = 0.f, rsc = 0.f;
        int rix = 0;
        if (tid < 64) {
            mlo[tid] = 0;
            mhi[tid] = 0;
            supp[tid] = (tid < nc) ? 0 : 1;
            if (tid < nc) {
                u64 key = seg[cs + tid];
                rix = (int)(0xFFFFFFFFu - (unsigned)(key & 0xFFFFFFFFull));
                rsc = __uint_as_float((unsigned)(key >> 32));
                rb = boxes4[rix];
                rar = (rb.z - rb.x) * (rb.w - rb.y);
                cbxS[tid] = rb;
                car[tid] = rar;
            }
        }
        __syncthreads();
        {
            int i = tid >> 4, jl = tid & 15;
            if (i < nc) {
                float4 x = cbxS[i];
                float xa = car[i];
                bool s = false;
                for (int j = jl; j < kept; j += 16) {
                    float4 kb = kboxS[j];
                    if (iou_gt(kb.x, kb.y, kb.z, kb.w, karea[j],
                               x.x, x.y, x.z, x.w, xa)) { s = true; break; }
                }
                if (s) supp[i] = 1;
            }
        }
        {
            int i = tid & 63, jb2 = tid >> 6;
            if (i < nc) {
                float4 b = cbxS[i];
                float ba = car[i];
                unsigned int l32 = 0, h32 = 0;
                for (int j = jb2; j < nc; j += 16) {
                    if (j > i) {
                        float4 o = cbxS[j];
                        if (iou_gt(b.x, b.y, b.z, b.w, ba,
                                   o.x, o.y, o.z, o.w, car[j])) {
                            if (j < 32) l32 |= 1u << j;
                            else        h32 |= 1u << (j - 32);
                        }
                    }
                }
                if (l32) atomicOr(&mlo[i], l32);
                if (h32) atomicOr(&mhi[i], h32);
            }
        }
        __syncthreads();
        if (tid < 64) {
            bool alive = (lane < nc) && (supp[lane] == 0);
            unsigned int myLo = mlo[lane], myHi = mhi[lane];
            int kc = kept;
            while (kc < MAXDET) {
                u64 av = __ballot(alive);
                if (av == 0ull) break;
                int i = (int)__builtin_ctzll(av);
                unsigned int plo = (unsigned)__shfl((int)myLo, i, 64);
                unsigned int phi = (unsigned)__shfl((int)myHi, i, 64);
                u64 mi = ((u64)phi << 32) | plo;
                if (lane == i) {
                    kboxS[kc] = rb;
                    karea[kc] = rar;
                    size_t base = (size_t)c * A_N + (size_t)rix;
                    out[base] = rsc;
                    out[(size_t)CA_N + base] = (float)c;
                    size_t bo = (size_t)2 * CA_N + base * 4;
                    out[bo + 0] = rb.x;
                    out[bo + 1] = rb.y;
                    out[bo + 2] = rb.z;
                    out[bo + 3] = rb.w;
                    out[(size_t)6 * CA_N + base] = 1.0f;
                    alive = false;
                }
                if ((mi >> lane) & 1ull) alive = false;
                kc++;
            }
            if (lane == 0) *keptL = kc;
        }
        __syncthreads();
        kept = *keptL;
    }
    return kept;
}

// ---------------------------------------------------------------------------
// K4: register-resident serial greedy scan + output write.  80 blocks x 1024.
// Wave 0: per 64-chunk, lane l holds mask row (chunk*64+l) as 8 u64 VGPRs;
// each kept step = ctz + 16 v_readlane (SGPR broadcast) + ORs.  No LDS, no
// barriers, no bpermute in the loop.
// ---------------------------------------------------------------------------
__global__ __launch_bounds__(1024) void k_scan(const float* __restrict__ cls,
                                               const float* __restrict__ boxes,
                                               const int* __restrict__ gcnt,
                                               const u64* __restrict__ gkeys,
                                               const u64* __restrict__ maskG,
                                               const float4* __restrict__ winBox,
                                               const float* __restrict__ winArea,
                                               const float* __restrict__ winScr,
                                               const int* __restrict__ winIdx,
                                               float* __restrict__ out) {
    const int c = blockIdx.x;
    const int tid = threadIdx.x;
    const int lane = tid & 63;
    const float4* boxes4 = (const float4*)boxes;

    __shared__ u64 keysF[4096];          // 32 KB (fallback staging)
    __shared__ int cntb[NBIN], off[NBIN];
    __shared__ u64 keptmS[WORDS];
    __shared__ int keptShv, keptCtr, cntL, keptL;
    __shared__ float4 kboxS[MAXDET];
    __shared__ float karea[MAXDET];
    __shared__ float4 cbxS[64];
    __shared__ float car64[64];
    __shared__ unsigned int mlo[64], mhi[64];
    __shared__ unsigned char supp[64];

    if (tid < NBIN) {
        int v = gcnt[(c * NBIN + tid) * CNT_STRIDE];
        cntb[tid] = v > BCAP ? BCAP : v;
    }
    if (tid == 0) keptCtr = 0;
    __syncthreads();
    if (tid < NBIN) {
        int s = 0;
        for (int bb = NBIN - 1; bb > tid; --bb) s += cntb[bb];
        off[tid] = s;
    }
    __syncthreads();
    const int N = off[0] + cntb[0];
    const int NW = N < W_N ? N : W_N;

    if (tid < 64) {
        int kept = 0;
        u64 rem0 = 0, rem1 = 0, rem2 = 0, rem3 = 0, rem4 = 0, rem5 = 0, rem6 = 0, rem7 = 0;
        u64 km0 = 0, km1 = 0, km2 = 0, km3 = 0, km4 = 0, km5 = 0, km6 = 0, km7 = 0;
        const u64* mg = maskG + (size_t)c * WORDS * W_N;

#define SCAN_CHUNK(W0)                                                        \
        if (W0 * 64 < NW && kept < MAXDET) {                                  \
            u64 r0 = mg[0 * W_N + W0 * 64 + lane];                            \
            u64 r1 = mg[1 * W_N + W0 * 64 + lane];                            \
            u64 r2 = mg[2 * W_N + W0 * 64 + lane];                            \
            u64 r3 = mg[3 * W_N + W0 * 64 + lane];                            \
            u64 r4 = mg[4 * W_N + W0 * 64 + lane];                            \
            u64 r5 = mg[5 * W_N + W0 * 64 + lane];                            \
            u64 r6 = mg[6 * W_N + W0 * 64 + lane];                            \
            u64 r7 = mg[7 * W_N + W0 * 64 + lane];                            \
            int nb = NW - W0 * 64;                                            \
            u64 valw = nb >= 64 ? ~0ull : ((1ull << nb) - 1ull);              \
            u64 alive = ~rem##W0 & valw;                                      \
            while (alive && kept < MAXDET) {                                  \
                int ii = (int)__builtin_ctzll(alive);                         \
                u64 q0 = readlane64(r0, ii);                                  \
                u64 q1 = readlane64(r1, ii);                                  \
                u64 q2 = readlane64(r2, ii);                                  \
                u64 q3 = readlane64(r3, ii);                                  \
                u64 q4 = readlane64(r4, ii);                                  \
                u64 q5 = readlane64(r5, ii);                                  \
                u64 q6 = readlane64(r6, ii);                                  \
                u64 q7 = readlane64(r7, ii);                                  \
                rem0 |= q0; rem1 |= q1; rem2 |= q2; rem3 |= q3;               \
                rem4 |= q4; rem5 |= q5; rem6 |= q6; rem7 |= q7;               \
                km##W0 |= 1ull << ii;                                         \
                kept++;                                                       \
                alive &= ~(q##W0 | (1ull << ii));                             \
            }                                                                 \
        }

        SCAN_CHUNK(0)
        SCAN_CHUNK(1)
        SCAN_CHUNK(2)
        SCAN_CHUNK(3)
        SCAN_CHUNK(4)
        SCAN_CHUNK(5)
        SCAN_CHUNK(6)
        SCAN_CHUNK(7)
#undef SCAN_CHUNK

        if (lane == 0) {
            keptmS[0] = km0; keptmS[1] = km1; keptmS[2] = km2; keptmS[3] = km3;
            keptmS[4] = km4; keptmS[5] = km5; keptmS[6] = km6; keptmS[7] = km7;
            keptShv = kept;
        }
    }
    __syncthreads();

    // --- write kept window entries; also stash for fallback suppression ----
    for (int i = tid; i < NW; i += 1024) {
        if ((keptmS[i >> 6] >> (i & 63)) & 1ull) {
            float4 bx = winBox[c * W_N + i];
            int a = winIdx[c * W_N + i];
            int slot = atomicAdd(&keptCtr, 1);
            kboxS[slot] = bx;
            karea[slot] = winArea[c * W_N + i];
            size_t base = (size_t)c * A_N + (size_t)a;
            out[base] = winScr[c * W_N + i];
            out[(size_t)CA_N + base] = (float)c;
            size_t bo = (size_t)2 * CA_N + base * 4;
            out[bo + 0] = bx.x;
            out[bo + 1] = bx.y;
            out[bo + 2] = bx.z;
            out[bo + 3] = bx.w;
            out[(size_t)6 * CA_N + base] = 1.0f;
        }
    }
    __syncthreads();
    int kept = keptShv;

    // --- fallback 1: band-0 candidates beyond the window (rare) ------------
    if (kept < MAXDET && N > NW) {
        for (int t2 = NW + tid; t2 < N; t2 += 1024) {
            int b = NBIN - 1;
            for (; b >= 0; --b)
                if (t2 >= off[b] && t2 < off[b] + cntb[b]) break;
            keysF[t2 - NW] = gkeys[((size_t)(c * NBIN + b) << 8) + (t2 - off[b])];
        }
        __syncthreads();
        kept = resolve_run(keysF, N - NW, kept, boxes4, out, c,
                           kboxS, karea, cbxS, car64, mlo, mhi, supp, &keptL,
                           tid, lane);
    }

    // --- fallback 2: score bands below 0.975 (never in practice) -----------
    if (kept < MAXDET) {
        for (int band = 1;; ++band) {
            float hiB = band_lo(band - 1);
            float lo = band_lo(band);
            bool last = (lo <= 0.1f);
            float loEff = last ? 0.1f : lo;
            if (tid == 0) cntL = 0;
            __syncthreads();
            for (int a = tid; a < A_N; a += 1024) {
                float s = cls[(size_t)a * C_N + c];
                if (s > loEff && s <= hiB) {
                    int p = atomicAdd(&cntL, 1);
                    if (p < 4096)
                        keysF[p] = ((u64)__float_as_uint(s) << 32) |
                                   (u64)(0xFFFFFFFFu - (unsigned)a);
                }
            }
            __syncthreads();
            int cnt = cntL < 4096 ? cntL : 4096;
            int n2 = 64;
            while (n2 < cnt) n2 <<= 1;
            for (int i = cnt + tid; i < n2; i += 1024) keysF[i] = 0ull;
            __syncthreads();
            for (int k = 2; k <= n2; k <<= 1) {
                for (int j = k >> 1; j > 0; j >>= 1) {
                    for (int i = tid; i < n2; i += 1024) {
                        int ixj = i ^ j;
                        if (ixj > i) {
                            u64 u = keysF[i], v = keysF[ixj];
                            bool up = ((i & k) == 0);
                            if (up ? (u < v) : (u > v)) { keysF[i] = v; keysF[ixj] = u; }
                        }
                    }
                    __syncthreads();
                }
            }
            kept = resolve_run(keysF, cnt, kept, boxes4, out, c,
                               kboxS, karea, cbxS, car64, mlo, mhi, supp, &keptL,
                               tid, lane);
            if (kept >= MAXDET || last) break;
        }
    }
}

extern "C" void kernel_launch(void* const* d_in, const int* in_sizes, int n_in,
                              void* d_out, int out_size, void* d_ws, size_t ws_size,
                              hipStream_t stream) {
    const float* cls = (const float*)d_in[0];   // [1, A, C]
    const float* reg = (const float*)d_in[1];   // [1, A, 4]
    const float* anc = (const float*)d_in[2];   // [A, 4]
    float* out = (float*)d_out;

    // workspace layout (~7.8 MB), all offsets 16B-aligned
    char* w8 = (char*)d_ws;
    const size_t SZ_GCNT = (size_t)C_N * NBIN * CNT_STRIDE * 4;      // 163840
    const size_t SZ_BOX  = (size_t)A_N * 4 * 4;                       // 1227600
    const size_t SZ_GK   = (size_t)C_N * NBIN * BCAP * 8;             // 2621440
    const size_t SZ_WB   = (size_t)C_N * W_N * 16;                    // 655360
    const size_t SZ_WF   = (size_t)C_N * W_N * 4;                     // 163840

    int*    gcnt    = (int*)w8;
    float*  boxes   = (float*)(w8 + SZ_GCNT);
    u64*    gkeys   = (u64*)(w8 + SZ_GCNT + SZ_BOX);
    float4* winBox  = (float4*)(w8 + SZ_GCNT + SZ_BOX + SZ_GK);
    float*  winArea = (float*)(w8 + SZ_GCNT + SZ_BOX + SZ_GK + SZ_WB);
    float*  winScr  = (float*)(w8 + SZ_GCNT + SZ_BOX + SZ_GK + SZ_WB + SZ_WF);
    int*    winIdx  = (int*)(w8 + SZ_GCNT + SZ_BOX + SZ_GK + SZ_WB + 2 * SZ_WF);
    u64*    maskG   = (u64*)(w8 + SZ_GCNT + SZ_BOX + SZ_GK + SZ_WB + 3 * SZ_WF);

    hipMemsetAsync(gcnt, 0, SZ_GCNT, stream);

    const int nblocks = (CA_N + 255) / 256;
    k_prep<<<nblocks, 256, 0, stream>>>(cls, reg, anc, boxes, gcnt, gkeys,
                                        (float4*)d_out, nblocks * 256);

    k_sortgather<<<C_N, 1024, 0, stream>>>(gcnt, gkeys, (const float4*)boxes,
                                           winBox, winArea, winScr, winIdx);

    k_mask<<<dim3(WORDS, C_N), 256, 0, stream>>>(gcnt, winBox, winArea, maskG);

    k_scan<<<C_N, 1024, 0, stream>>>(cls, boxes, gcnt, gkeys, maskG,
                                     winBox, winArea, winScr, winIdx, out);
}

// Round 7
// 270.606 us; speedup vs baseline: 1.1817x; 1.1275x over previous
//
#include <hip/hip_runtime.h>
#include <cstdint>
#include <cstddef>

#pragma clang fp contract(off)

#define A_N 76725
#define C_N 80
#define CA_N (A_N * 80)           // 6,138,000
#define MAXDET 200
#define NBIN 16
#define BCAP 256                  // per-bin capacity (expected ~120, +12 sigma)
#define W_N 320                   // mask-NMS window (survivor margin: ~305 > 200)
#define WORDS 5                   // W_N / 64
#define IMG_F 640.0f
#define THR0 0.975f
#define CNT_STRIDE 32             // ints; 128 B per counter -> own L2 line
#define FILLB 2480                // fill-role blocks in k_mega

typedef unsigned long long u64;

// ---------------------------------------------------------------------------
// IoU predicate — exact op sequence of the reference.
// ---------------------------------------------------------------------------
__device__ __forceinline__ bool iou_gt(float b0, float b1, float b2, float b3, float ab,
                                       float x0, float x1, float x2, float x3, float xa) {
    float ix1 = fmaxf(b0, x0);
    float iy1 = fmaxf(b1, x1);
    float ix2 = fminf(b2, x2);
    float iy2 = fminf(b3, x3);
    float iw = fmaxf(ix2 - ix1, 0.0f);
    float ih = fmaxf(iy2 - iy1, 0.0f);
    float inter = iw * ih;
    float den = ab + xa - inter;
    float iou = inter / den;
    return iou > 0.5f;
}

__device__ __forceinline__ float band_lo(int b) {
    return 0.975f - 0.025f * (float)b;
}

__device__ __forceinline__ u64 readlane64(u64 v, int src) {
    unsigned lo = __builtin_amdgcn_readlane((unsigned)v, src);
    unsigned hi = __builtin_amdgcn_readlane((unsigned)(v >> 32), src);
    return ((u64)hi << 32) | lo;
}

// ---------------------------------------------------------------------------
// K1: decode + 16-way sub-band candidate select (monotone bin(s) preserves
// global greedy order; ties share a bin).
// ---------------------------------------------------------------------------
__global__ __launch_bounds__(256) void k_prep(const float* __restrict__ cls,
                                              const float* __restrict__ reg,
                                              const float* __restrict__ anc,
                                              float* __restrict__ boxes,
                                              int* __restrict__ gcnt,
                                              u64* __restrict__ gkeys) {
    int i = blockIdx.x * 256 + threadIdx.x;
    if (i < A_N) {
        float a0 = anc[i * 4 + 0], a1 = anc[i * 4 + 1];
        float a2 = anc[i * 4 + 2], a3 = anc[i * 4 + 3];
        float aw = a2 - a0;
        float ah = a3 - a1;
        float ax = a0 + 0.5f * aw;
        float ay = a1 + 0.5f * ah;
        float r0 = reg[i * 4 + 0], r1 = reg[i * 4 + 1];
        float r2 = reg[i * 4 + 2], r3 = reg[i * 4 + 3];
        float cx = ax + r0 * 0.1f * aw;
        float cy = ay + r1 * 0.1f * ah;
        float w = aw * expf(r2 * 0.2f);
        float h = ah * expf(r3 * 0.2f);
        float x1 = fminf(fmaxf(cx - 0.5f * w, 0.0f), IMG_F);
        float y1 = fminf(fmaxf(cy - 0.5f * h, 0.0f), IMG_F);
        float x2 = fminf(fmaxf(cx + 0.5f * w, 0.0f), IMG_F);
        float y2 = fminf(fmaxf(cy + 0.5f * h, 0.0f), IMG_F);
        boxes[i * 4 + 0] = x1;
        boxes[i * 4 + 1] = y1;
        boxes[i * 4 + 2] = x2;
        boxes[i * 4 + 3] = y2;
    }
    if (i < CA_N) {
        float s = cls[i];
        if (s > THR0) {
            int c = i % C_N;
            unsigned a = (unsigned)(i / C_N);
            int b = (int)((s - THR0) * 640.0f);
            b = b < 0 ? 0 : (b > (NBIN - 1) ? (NBIN - 1) : b);
            int slot = atomicAdd(&gcnt[(c * NBIN + b) * CNT_STRIDE], 1);
            if (slot < BCAP)
                gkeys[((size_t)(c * NBIN + b) << 8) + slot] =
                    ((u64)__float_as_uint(s) << 32) | (u64)(0xFFFFFFFFu - a);
        }
    }
}

// ---------------------------------------------------------------------------
// Chunk-of-64 greedy resolve over a sorted descending run (fallback only).
// Appends kept records to the LDS record arrays.
// ---------------------------------------------------------------------------
__device__ __forceinline__ int resolve_run(const u64* seg, int cnt, int kept,
                                           const float4* __restrict__ boxes4,
                                           float4* kboxS, float* karea,
                                           int* kIdxL, float* kScrL,
                                           float4* cbxS, float* car64,
                                           unsigned int* mlo, unsigned int* mhi,
                                           unsigned char* supp, int* keptL,
                                           int tid, int lane) {
    for (int cs = 0; cs < cnt && kept < MAXDET; cs += 64) {
        int nc = (cnt - cs < 64) ? (cnt - cs) : 64;
        float4 rb = make_float4(0.f, 0.f, 0.f, 0.f);
        float rar = 0.f, rsc = 0.f;
        int rix = 0;
        if (tid < 64) {
            mlo[tid] = 0;
            mhi[tid] = 0;
            supp[tid] = (tid < nc) ? 0 : 1;
            if (tid < nc) {
                u64 key = seg[cs + tid];
                rix = (int)(0xFFFFFFFFu - (unsigned)(key & 0xFFFFFFFFull));
                rsc = __uint_as_float((unsigned)(key >> 32));
                rb = boxes4[rix];
                rar = (rb.z - rb.x) * (rb.w - rb.y);
                cbxS[tid] = rb;
                car64[tid] = rar;
            }
        }
        __syncthreads();
        {
            int i = tid >> 4, jl = tid & 15;
            if (i < nc) {
                float4 x = cbxS[i];
                float xa = car64[i];
                bool s = false;
                for (int j = jl; j < kept; j += 16) {
                    float4 kb = kboxS[j];
                    if (iou_gt(kb.x, kb.y, kb.z, kb.w, karea[j],
                               x.x, x.y, x.z, x.w, xa)) { s = true; break; }
                }
                if (s) supp[i] = 1;
            }
        }
        {
            int i = tid & 63, jb2 = tid >> 6;
            if (i < nc) {
                float4 b = cbxS[i];
                float ba = car64[i];
                unsigned int l32 = 0, h32 = 0;
                for (int j = jb2; j < nc; j += 16) {
                    if (j > i) {
                        float4 o = cbxS[j];
                        if (iou_gt(b.x, b.y, b.z, b.w, ba,
                                   o.x, o.y, o.z, o.w, car64[j])) {
                            if (j < 32) l32 |= 1u << j;
                            else        h32 |= 1u << (j - 32);
                        }
                    }
                }
                if (l32) atomicOr(&mlo[i], l32);
                if (h32) atomicOr(&mhi[i], h32);
            }
        }
        __syncthreads();
        if (tid < 64) {
            bool alive = (lane < nc) && (supp[lane] == 0);
            unsigned int myLo = mlo[lane], myHi = mhi[lane];
            int kc = kept;
            while (kc < MAXDET) {
                u64 av = __ballot(alive);
                if (av == 0ull) break;
                int i = (int)__builtin_ctzll(av);
                unsigned int plo = (unsigned)__shfl((int)myLo, i, 64);
                unsigned int phi = (unsigned)__shfl((int)myHi, i, 64);
                u64 mi = ((u64)phi << 32) | plo;
                if (lane == i) {
                    kboxS[kc] = rb;
                    karea[kc] = rar;
                    kIdxL[kc] = rix;
                    kScrL[kc] = rsc;
                    alive = false;
                }
                if ((mi >> lane) & 1ull) alive = false;
                kc++;
            }
            if (lane == 0) *keptL = kc;
        }
        __syncthreads();
        kept = *keptL;
    }
    return kept;
}

// ---------------------------------------------------------------------------
// K2: heterogeneous mega-kernel.
//   blocks [0, C_N)        : full per-class NMS in LDS -> kept records to ws
//   blocks [C_N, C_N+FILLB): grid-stride default-fill of all outputs
// Fill (HBM-bound) overlaps NMS (latency-bound, ~25 us on 80 CUs).
// ---------------------------------------------------------------------------
__global__ __launch_bounds__(1024) void k_mega(const float* __restrict__ cls,
                                               const float* __restrict__ boxes,
                                               const int* __restrict__ gcnt,
                                               const u64* __restrict__ gkeys,
                                               int* __restrict__ kcnt,
                                               int* __restrict__ kidx,
                                               float* __restrict__ kscr,
                                               float* __restrict__ kboxg,
                                               float4* __restrict__ out4) {
    const int tid = threadIdx.x;

    if (blockIdx.x >= C_N) {
        // ---------------- fill role ----------------------------------------
        int fb = blockIdx.x - C_N;
        const int n4 = (7 * CA_N) / 4;
        const int lab_lo = CA_N / 4;
        const int lab_hi = (2 * CA_N) / 4;
        for (int i = fb * 1024 + tid; i < n4; i += FILLB * 1024) {
            float v = (i >= lab_lo && i < lab_hi) ? -1.0f : 0.0f;
            out4[i] = make_float4(v, v, v, v);
        }
        return;
    }

    // ---------------- NMS role ---------------------------------------------
    const int c = blockIdx.x;
    const int wave = tid >> 6, lane = tid & 63;
    const float4* boxes4 = (const float4*)boxes;

    __shared__ u64 buf[NBIN][BCAP];      // 32 KB (bins; reused by fallback-2)
    __shared__ u64 maskS[W_N * WORDS];   // 12.5 KB
    __shared__ float4 cbx[W_N];          // 5 KB
    __shared__ float car[W_N];           // 1.25 KB
    __shared__ float cscr[W_N];
    __shared__ int cidx[W_N];
    __shared__ float4 kboxS[MAXDET];
    __shared__ float karea[MAXDET];
    __shared__ int kIdxL[MAXDET];
    __shared__ float kScrL[MAXDET];
    __shared__ float4 cbxS[64];
    __shared__ float car64[64];
    __shared__ unsigned int mlo[64], mhi[64];
    __shared__ unsigned char supp[64];
    __shared__ int cntb[NBIN], off[NBIN];
    __shared__ u64 kmS[WORDS];
    __shared__ int keptShv, keptCtr, cntL, keptL;

    // --- bin counts + offsets ----------------------------------------------
    if (tid < NBIN) {
        int v = gcnt[(c * NBIN + tid) * CNT_STRIDE];
        cntb[tid] = v > BCAP ? BCAP : v;
    }
    if (tid == 0) keptCtr = 0;
    __syncthreads();
    if (tid < NBIN) {
        int s = 0;
        for (int bb = NBIN - 1; bb > tid; --bb) s += cntb[bb];
        off[tid] = s;
    }
    __syncthreads();
    const int N = off[0] + cntb[0];
    const int NW = N < W_N ? N : W_N;

    // --- per-wave bin sort in LDS (desc; wave-synchronous bitonic) ----------
    {
        int cw = cntb[wave];
        volatile u64* seg = buf[wave];
        const u64* src = gkeys + ((size_t)(c * NBIN + wave) << 8);
        for (int i = lane; i < cw; i += 64) seg[i] = src[i];
        int n2 = 64;
        while (n2 < cw) n2 <<= 1;
        for (int i = cw + lane; i < n2; i += 64) seg[i] = 0ull;
        __builtin_amdgcn_wave_barrier();
        for (int k = 2; k <= n2; k <<= 1) {
            for (int j = k >> 1; j > 0; j >>= 1) {
                for (int i0 = lane; i0 < n2; i0 += 64) {
                    int ixj = i0 ^ j;
                    if (ixj > i0) {
                        u64 u = seg[i0], v = seg[ixj];
                        bool up = ((i0 & k) == 0);
                        if (up ? (u < v) : (u > v)) { seg[i0] = v; seg[ixj] = u; }
                    }
                }
                __builtin_amdgcn_wave_barrier();
            }
        }
    }
    __syncthreads();

    // --- gather window (global sorted order: bin 15 first) ------------------
    for (int i = tid; i < NW; i += 1024) {
        int b = NBIN - 1;
        for (; b >= 0; --b)
            if (i >= off[b] && i < off[b] + cntb[b]) break;
        u64 key = buf[b][i - off[b]];
        int a = (int)(0xFFFFFFFFu - (unsigned)(key & 0xFFFFFFFFull));
        float4 bx = boxes4[a];
        cbx[i] = bx;
        car[i] = (bx.z - bx.x) * (bx.w - bx.y);
        cscr[i] = __uint_as_float((unsigned)(key >> 32));
        cidx[i] = a;
    }
    __syncthreads();

    // --- mask build: row-word (r, w); upper-triangular --------------------
    for (int idx = tid; idx < W_N * WORDS; idx += 1024) {
        int r = idx / WORDS, w = idx - r * WORDS;
        u64 m = 0;
        if (r < NW) {
            int jbase = w * 64;
            int jend = (NW - jbase) < 64 ? (NW - jbase) : 64;
            if (jend > 0 && jbase + 63 > r) {
                float4 rb = cbx[r];
                float ra = car[r];
                for (int jj = 0; jj < jend; ++jj) {
                    int jg = jbase + jj;
                    if (jg > r) {
                        float4 o = cbx[jg];
                        if (iou_gt(rb.x, rb.y, rb.z, rb.w, ra,
                                   o.x, o.y, o.z, o.w, car[jg]))
                            m |= 1ull << jj;
                    }
                }
            }
        }
        maskS[idx] = m;
    }
    __syncthreads();

    // --- register-resident serial scan (wave 0; no LDS in the loop) --------
    if (tid < 64) {
        int kept = 0;
        u64 rem0 = 0, rem1 = 0, rem2 = 0, rem3 = 0, rem4 = 0;
        u64 km0 = 0, km1 = 0, km2 = 0, km3 = 0, km4 = 0;

#define SCAN_CHUNK(W0)                                                        \
        if (W0 * 64 < NW && kept < MAXDET) {                                  \
            int r = W0 * 64 + lane;                                           \
            u64 r0 = maskS[r * WORDS + 0];                                    \
            u64 r1 = maskS[r * WORDS + 1];                                    \
            u64 r2 = maskS[r * WORDS + 2];                                    \
            u64 r3 = maskS[r * WORDS + 3];                                    \
            u64 r4 = maskS[r * WORDS + 4];                                    \
            int nb = NW - W0 * 64;                                            \
            u64 valw = nb >= 64 ? ~0ull : ((1ull << nb) - 1ull);              \
            u64 alive = ~rem##W0 & valw;                                      \
            while (alive && kept < MAXDET) {                                  \
                int ii = (int)__builtin_ctzll(alive);                         \
                u64 q0 = readlane64(r0, ii);                                  \
                u64 q1 = readlane64(r1, ii);                                  \
                u64 q2 = readlane64(r2, ii);                                  \
                u64 q3 = readlane64(r3, ii);                                  \
                u64 q4 = readlane64(r4, ii);                                  \
                rem0 |= q0; rem1 |= q1; rem2 |= q2; rem3 |= q3; rem4 |= q4;   \
                km##W0 |= 1ull << ii;                                         \
                kept++;                                                       \
                alive &= ~(q##W0 | (1ull << ii));                             \
            }                                                                 \
        }

        SCAN_CHUNK(0)
        SCAN_CHUNK(1)
        SCAN_CHUNK(2)
        SCAN_CHUNK(3)
        SCAN_CHUNK(4)
#undef SCAN_CHUNK

        if (lane == 0) {
            kmS[0] = km0; kmS[1] = km1; kmS[2] = km2; kmS[3] = km3; kmS[4] = km4;
            keptShv = kept;
        }
    }
    __syncthreads();

    // --- window-kept -> LDS record arrays -----------------------------------
    for (int i = tid; i < NW; i += 1024) {
        if ((kmS[i >> 6] >> (i & 63)) & 1ull) {
            int slot = atomicAdd(&keptCtr, 1);
            kboxS[slot] = cbx[i];
            karea[slot] = car[i];
            kIdxL[slot] = cidx[i];
            kScrL[slot] = cscr[i];
        }
    }
    __syncthreads();
    int kept = keptShv;

    // --- fallback 1: band-0 beyond the window (runs from sorted LDS bins) ---
    if (kept < MAXDET && N > NW) {
        for (int b = NBIN - 1; b >= 0 && kept < MAXDET; --b) {
            int s0 = off[b], sz = cntb[b];
            int start = NW > s0 ? (NW - s0) : 0;
            if (start < sz)
                kept = resolve_run((const u64*)buf[b] + start, sz - start, kept,
                                   boxes4, kboxS, karea, kIdxL, kScrL,
                                   cbxS, car64, mlo, mhi, supp, &keptL,
                                   tid, lane);
        }
    }

    // --- fallback 2: score bands below 0.975 (never in practice) ------------
    if (kept < MAXDET) {
        u64* keysF = &buf[0][0];         // 4096-u64 staging (bins are dead)
        for (int band = 1;; ++band) {
            float hiB = band_lo(band - 1);
            float lo = band_lo(band);
            bool last = (lo <= 0.1f);
            float loEff = last ? 0.1f : lo;
            if (tid == 0) cntL = 0;
            __syncthreads();
            for (int a = tid; a < A_N; a += 1024) {
                float s = cls[(size_t)a * C_N + c];
                if (s > loEff && s <= hiB) {
                    int p = atomicAdd(&cntL, 1);
                    if (p < 4096)
                        keysF[p] = ((u64)__float_as_uint(s) << 32) |
                                   (u64)(0xFFFFFFFFu - (unsigned)a);
                }
            }
            __syncthreads();
            int cnt = cntL < 4096 ? cntL : 4096;
            int n2 = 64;
            while (n2 < cnt) n2 <<= 1;
            for (int i = cnt + tid; i < n2; i += 1024) keysF[i] = 0ull;
            __syncthreads();
            for (int k = 2; k <= n2; k <<= 1) {
                for (int j = k >> 1; j > 0; j >>= 1) {
                    for (int i = tid; i < n2; i += 1024) {
                        int ixj = i ^ j;
                        if (ixj > i) {
                            u64 u = keysF[i], v = keysF[ixj];
                            bool up = ((i & k) == 0);
                            if (up ? (u < v) : (u > v)) { keysF[i] = v; keysF[ixj] = u; }
                        }
                    }
                    __syncthreads();
                }
            }
            kept = resolve_run(keysF, cnt, kept, boxes4,
                               kboxS, karea, kIdxL, kScrL,
                               cbxS, car64, mlo, mhi, supp, &keptL, tid, lane);
            if (kept >= MAXDET || last) break;
        }
    }

    // --- write kept records to workspace ------------------------------------
    if (tid == 0) kcnt[c] = kept;
    for (int i = tid; i < kept; i += 1024) {
        kidx[c * MAXDET + i] = kIdxL[i];
        kscr[c * MAXDET + i] = kScrL[i];
        float4 kb = kboxS[i];
        kboxg[(c * MAXDET + i) * 4 + 0] = kb.x;
        kboxg[(c * MAXDET + i) * 4 + 1] = kb.y;
        kboxg[(c * MAXDET + i) * 4 + 2] = kb.z;
        kboxg[(c * MAXDET + i) * 4 + 3] = kb.w;
    }
}

// ---------------------------------------------------------------------------
// K3: scatter kept entries into outputs (defaults already written by k_mega)
// ---------------------------------------------------------------------------
__global__ __launch_bounds__(256) void k_scatter(const int* __restrict__ kcnt,
                                                 const int* __restrict__ kidx,
                                                 const float* __restrict__ kscr,
                                                 const float* __restrict__ kboxg,
                                                 float* __restrict__ out) {
    int c = blockIdx.x, t = threadIdx.x;
    int k = kcnt[c];
    for (int i = t; i < k; i += 256) {
        int a = kidx[c * MAXDET + i];
        size_t base = (size_t)c * A_N + (size_t)a;
        out[base] = kscr[c * MAXDET + i];                // final_scores
        out[(size_t)CA_N + base] = (float)c;             // final_labels
        size_t bo = (size_t)2 * CA_N + base * 4;         // final_boxes
        out[bo + 0] = kboxg[(c * MAXDET + i) * 4 + 0];
        out[bo + 1] = kboxg[(c * MAXDET + i) * 4 + 1];
        out[bo + 2] = kboxg[(c * MAXDET + i) * 4 + 2];
        out[bo + 3] = kboxg[(c * MAXDET + i) * 4 + 3];
        out[(size_t)6 * CA_N + base] = 1.0f;             // keep
    }
}

extern "C" void kernel_launch(void* const* d_in, const int* in_sizes, int n_in,
                              void* d_out, int out_size, void* d_ws, size_t ws_size,
                              hipStream_t stream) {
    const float* cls = (const float*)d_in[0];   // [1, A, C]
    const float* reg = (const float*)d_in[1];   // [1, A, 4]
    const float* anc = (const float*)d_in[2];   // [A, 4]
    float* out = (float*)d_out;

    // workspace layout (~4.8 MB)
    int* gcnt = (int*)d_ws;                                  // C*NBIN*CNT_STRIDE ints
    float* boxes = (float*)(gcnt + C_N * NBIN * CNT_STRIDE); // 4*A floats
    u64* gkeys = (u64*)(boxes + 4 * A_N);                    // C*NBIN*BCAP u64
    int* kcnt = (int*)(gkeys + (size_t)C_N * NBIN * BCAP);   // C ints
    int* kidx = kcnt + C_N;                                  // C*MAXDET ints
    float* kscr = (float*)(kidx + C_N * MAXDET);             // C*MAXDET floats
    float* kboxg = kscr + C_N * MAXDET;                      // C*MAXDET*4 floats

    hipMemsetAsync(gcnt, 0, C_N * NBIN * CNT_STRIDE * sizeof(int), stream);

    k_prep<<<(CA_N + 255) / 256, 256, 0, stream>>>(cls, reg, anc, boxes, gcnt, gkeys);

    k_mega<<<C_N + FILLB, 1024, 0, stream>>>(cls, boxes, gcnt, gkeys,
                                             kcnt, kidx, kscr, kboxg, (float4*)d_out);

    k_scatter<<<C_N, 256, 0, stream>>>(kcnt, kidx, kscr, kboxg, out);
}